// Round 10
// baseline (90.665 us; speedup 1.0000x reference)
//
#include <hip/hip_runtime.h>
#include <math.h>

#define BLOCK 64
#define BATCH 16384
#define EPB 8      // elements per block: 8 lanes per element
#define EP 9       // element-dim stride for per-element LDS arrays
#define NDOF 7
#define ACTION_RANGE 50.0f
#define MAX_VEL 20.0f
#define HSTEP 0.1f

// BLOCK==64 -> exactly one wave per workgroup. DS ops from a single wave are
// processed in order by the LDS pipe, so cross-lane LDS communication needs
// no s_barrier — only a compiler fence to forbid reordering. (Validated:
// R14-R22 all passed the harness with this scheme.)
#define WSYNC() asm volatile("" ::: "memory")
// Bound scheduler lookahead at joint-iteration boundaries (measured neutral
// vs none, R17 vs R20; kept because R17/R22 is the best-measured config).
#define SCHED_FENCE() __builtin_amdgcn_sched_barrier(0)

__device__ __forceinline__ void mat3_mul(float* C, const float* A, const float* B) {
#pragma unroll
  for (int r = 0; r < 3; r++) {
#pragma unroll
    for (int c = 0; c < 3; c++) {
      C[r*3+c] = A[r*3+0]*B[0*3+c] + A[r*3+1]*B[1*3+c] + A[r*3+2]*B[2*3+c];
    }
  }
}

__device__ __forceinline__ void mat3_vec(float* y, const float* A, const float* x) {
#pragma unroll
  for (int r = 0; r < 3; r++)
    y[r] = A[r*3+0]*x[0] + A[r*3+1]*x[1] + A[r*3+2]*x[2];
}

__device__ __forceinline__ void mat3T_vec(float* y, const float* A, const float* x) {
#pragma unroll
  for (int r = 0; r < 3; r++)
    y[r] = A[0*3+r]*x[0] + A[1*3+r]*x[1] + A[2*3+r]*x[2];
}

__device__ __forceinline__ void cross3(float* y, const float* a, const float* b) {
  y[0] = a[1]*b[2] - a[2]*b[1];
  y[1] = a[2]*b[0] - a[0]*b[2];
  y[2] = a[0]*b[1] - a[1]*b[0];
}

// Rodrigues-direct for UNIT axis w (W^2 = ww^T - I):
//   R = cI + sW + (1-c)ww^T ;  G v with G = sI + (1-c)W + (th-s)ww^T
__device__ __forceinline__ void exp_se3(const float* A6, float th, float* R, float* p) {
  float w0 = A6[0], w1 = A6[1], w2 = A6[2];
  float s = __sinf(th);
  float c = __cosf(th);
  float omc = 1.0f - c, tms = th - s;
  float p00 = w0*w0, p01 = w0*w1, p02 = w0*w2;
  float p11 = w1*w1, p12 = w1*w2, p22 = w2*w2;
  R[0] = c + omc*p00;       R[1] = omc*p01 - s*w2;   R[2] = omc*p02 + s*w1;
  R[3] = omc*p01 + s*w2;    R[4] = c + omc*p11;      R[5] = omc*p12 - s*w0;
  R[6] = omc*p02 - s*w1;    R[7] = omc*p12 + s*w0;   R[8] = c + omc*p22;
  float G0 = s + tms*p00,    G1 = tms*p01 - omc*w2,  G2 = tms*p02 + omc*w1;
  float G3 = tms*p01 + omc*w2, G4 = s + tms*p11,     G5 = tms*p12 - omc*w0;
  float G6 = tms*p02 - omc*w1, G7 = tms*p12 + omc*w0, G8 = s + tms*p22;
  p[0] = G0*A6[3] + G1*A6[4] + G2*A6[5];
  p[1] = G3*A6[3] + G4*A6[4] + G5*A6[5];
  p[2] = G6*A6[3] + G7*A6[4] + G8*A6[5];
}

__device__ __forceinline__ float wrap_pi(float x) {
  const float PI_F   = 3.14159265358979323846f;
  const float TWO_PI = 6.28318530717958647692f;
  float a = x + PI_F;
  float r = a - floorf(a * (1.0f / TWO_PI)) * TWO_PI;
  return r - PI_F;
}

// R23 = R22 (best: harness 90.50us; scalar EP-stride LDS, ~112 VGPR natural,
// Bm-free adjoint, WSYNC wave-sync, per-joint fences, FK shuffle tree)
// + wave-PARALLEL solve: lane-7 serial LDL^T (-> ~370 serial cyc while 7
// lanes idle + qaccL LDS round-trip) replaced by 7-lane Gauss-Jordan on the
// SPD system. Lane r owns row r of [M | rhs]; 7 unrolled pivot steps of
// {shuffle-broadcast pivot row (cols k..7 only — cols <k are already 0),
// rcp, fused row update}. Lane r finishes holding qacc_r IN REGISTER:
// qaccL and tauL arrays + their round-trips are deleted; (D) fuses into (E).
// SPD => no pivoting needed. bias moves to biasL (7 ds_writes, lane 7).
// Closed axes (measured): TLP grid-capped (R21), float4 LDS (R18),
// hand-pipelining (R19), occupancy attrs (R15/R16). Spill sentinel: ~2MB.
__global__ __launch_bounds__(BLOCK, 1) void arm_rk4_kernel(
    const float* __restrict__ g_state, const float* __restrict__ g_action,
    const float* __restrict__ g_M, const float* __restrict__ g_A,
    const float* __restrict__ g_G, const float* __restrict__ g_grav,
    float* __restrict__ g_out_state, float* __restrict__ g_out_ee)
{
  __shared__ float sMR[8][9];
  __shared__ float sMp[8][3];
  __shared__ float sIR[7][9];
  __shared__ float sIp[7][3];
  __shared__ float sA[7][6];
  __shared__ float sG[7][4];
  __shared__ float sg[3];
  __shared__ float sRB[7*12*EP];   // per joint: R[9], Tp[3]
  __shared__ float sQh[7*6*EP];    // per joint: Vd (lane-7 history)
  __shared__ float biasL[NDOF*EP];
  __shared__ float MllL[28*EP];

  const int tid  = threadIdx.x;
  const int e    = tid >> 3;      // element slot 0..7
  const int r    = tid & 7;       // role 0..7
  const int base = tid & 0x38;    // first lane of this element group
  const int b    = blockIdx.x * EPB + e;

  if (tid < 8) {
    const float* Mi = g_M + tid*16;
    float a1[3] = {Mi[0], Mi[4], Mi[8]};
    float a2[3] = {Mi[1], Mi[5], Mi[9]};
    float p[3]  = {Mi[3], Mi[7], Mi[11]};
    float n1 = sqrtf(a1[0]*a1[0] + a1[1]*a1[1] + a1[2]*a1[2]);
    float b1[3] = {a1[0]/n1, a1[1]/n1, a1[2]/n1};
    float d = a2[0]*b1[0] + a2[1]*b1[1] + a2[2]*b1[2];
    float a2o[3] = {a2[0]-d*b1[0], a2[1]-d*b1[1], a2[2]-d*b1[2]};
    float n2 = sqrtf(a2o[0]*a2o[0] + a2o[1]*a2o[1] + a2o[2]*a2o[2]);
    float b2[3] = {a2o[0]/n2, a2o[1]/n2, a2o[2]/n2};
    float b3[3];
    cross3(b3, b1, b2);
    float R[9] = {b1[0], b2[0], b3[0],  b1[1], b2[1], b3[1],  b1[2], b2[2], b3[2]};
#pragma unroll
    for (int k = 0; k < 9; k++) sMR[tid][k] = R[k];
    sMp[tid][0] = p[0]; sMp[tid][1] = p[1]; sMp[tid][2] = p[2];
    if (tid < 7) {
#pragma unroll
      for (int rr = 0; rr < 3; rr++)
#pragma unroll
        for (int cc = 0; cc < 3; cc++) sIR[tid][rr*3+cc] = R[cc*3+rr];
#pragma unroll
      for (int rr = 0; rr < 3; rr++)
        sIp[tid][rr] = -(R[0*3+rr]*p[0] + R[1*3+rr]*p[1] + R[2*3+rr]*p[2]);
      const float* Ar = g_A + tid*6;
      float nw = sqrtf(Ar[0]*Ar[0] + Ar[1]*Ar[1] + Ar[2]*Ar[2]);
      sA[tid][0] = Ar[0]/nw; sA[tid][1] = Ar[1]/nw; sA[tid][2] = Ar[2]/nw;
      sA[tid][3] = Ar[3];    sA[tid][4] = Ar[4];    sA[tid][5] = Ar[5];
      sG[tid][0] = fabsf(g_G[tid*4+0]);
      sG[tid][1] = fabsf(g_G[tid*4+1]);
      sG[tid][2] = fabsf(g_G[tid*4+2]);
      sG[tid][3] = fabsf(g_G[tid*4+3]);
    }
  }
  if (tid == 0) { sg[0] = g_grav[0]; sg[1] = g_grav[1]; sg[2] = g_grav[2]; }

  float q0 = 0.f, dq0 = 0.f, qs = 0.f, dqs = 0.f, tau = 0.f;
  float accq = 0.f, accd = 0.f;
  if (r < NDOF) {
    q0  = g_state[b*14 + r];
    dq0 = g_state[b*14 + 7 + r];
    tau = g_action[b*7 + r] * ACTION_RANGE;
    qs = q0; dqs = dq0;
  }
  WSYNC();

#pragma unroll 1
  for (int st = 0; st < 4; st++) {
    // ---- (A) adjoint of joint r, lanes r<7: T = exp(-q A) * M^-1 ----
    if (r < NDOF) {
      float Ai[6];
#pragma unroll
      for (int k = 0; k < 6; k++) Ai[k] = sA[r][k];
      float Re[9], pe[3];
      exp_se3(Ai, -qs, Re, pe);
      float IRl[9];
#pragma unroll
      for (int k = 0; k < 9; k++) IRl[k] = sIR[r][k];
      float Tr9[9];
      mat3_mul(Tr9, Re, IRl);
      float Ipl[3] = {sIp[r][0], sIp[r][1], sIp[r][2]};
      float Tp[3];
      mat3_vec(Tp, Re, Ipl);
      Tp[0] += pe[0]; Tp[1] += pe[1]; Tp[2] += pe[2];
#pragma unroll
      for (int k = 0; k < 9; k++) sRB[(r*12 + k)*EP + e] = Tr9[k];
#pragma unroll
      for (int k = 0; k < 3; k++) sRB[(r*12 + 9 + k)*EP + e] = Tp[k];
    }
    WSYNC();
    SCHED_FENCE();

    // ---- (BC) fused forward+backward sweep, ALL 8 lanes ----
    {
      float Phw[NDOF][3], Phv[NDOF][3];
      float Pw[3] = {0.f,0.f,0.f}, Pv[3] = {0.f,0.f,0.f};
      float Qw[3] = {0.f,0.f,0.f}, Qv[3] = {0.f,0.f,0.f};
      if (r == 7) { Qv[0] = -sg[0]; Qv[1] = -sg[1]; Qv[2] = -sg[2]; }
#pragma unroll
      for (int i = 0; i < NDOF; i++) {
        float Rm[9], Tpl[3];
#pragma unroll
        for (int k = 0; k < 9; k++) Rm[k] = sRB[(i*12 + k)*EP + e];
#pragma unroll
        for (int k = 0; k < 3; k++) Tpl[k] = sRB[(i*12 + 9 + k)*EP + e];
        float dqi = __shfl(dqs, base + i, 64);
        float Aw[3] = {sA[i][0], sA[i][1], sA[i][2]};
        float Av[3] = {sA[i][3], sA[i][4], sA[i][5]};
        // P: Pw' = R Pw (+cA*Aw); Pv' = Tp x (R Pw) + R Pv (+cA*Av)
        float Tw[3], t2[3], Tv[3];
        mat3_vec(Tw, Rm, Pw);
        mat3_vec(t2, Rm, Pv);
        cross3(Tv, Tpl, Tw);
        float cA = (r == i) ? 1.f : ((r == 7) ? dqi : 0.f);
#pragma unroll
        for (int k = 0; k < 3; k++) {
          Pw[k] = Tw[k] + cA*Aw[k];
          Pv[k] = Tv[k] + t2[k] + cA*Av[k];
        }
        // Q = AdT*Q + dq_i * ad(P)A_i   (meaningful on lane 7 only)
        float Uw[3], u2[3], Uv[3];
        mat3_vec(Uw, Rm, Qw);
        mat3_vec(u2, Rm, Qv);
        cross3(Uv, Tpl, Uw);
        float c1[3], c2[3], c3[3];
        cross3(c1, Pw, Aw);
        cross3(c2, Pv, Aw);
        cross3(c3, Pw, Av);
        float c8 = (r == 7) ? dqi : 0.f;
#pragma unroll
        for (int k = 0; k < 3; k++) {
          Qw[k] = Uw[k] + c8*c1[k];
          Qv[k] = Uv[k] + u2[k] + c8*(c2[k]+c3[k]);
        }
        if (r == 7) {
#pragma unroll
          for (int k = 0; k < 3; k++) {
            sQh[(i*6 +     k)*EP + e] = Qw[k];
            sQh[(i*6 + 3 + k)*EP + e] = Qv[k];
          }
        }
#pragma unroll
        for (int k = 0; k < 3; k++) { Phw[i][k] = Pw[k]; Phv[i][k] = Pv[k]; }
        SCHED_FENCE();
      }
      // backward: F' = AdT^T F via R^T(Fw + Fv x Tp); R/Tp re-read from LDS
      float Fw[3] = {0.f, 0.f, 0.f}, Fv[3] = {0.f, 0.f, 0.f};
#pragma unroll
      for (int i = NDOF-1; i >= 0; i--) {
        if (i < NDOF-1) {
          const int jn = i + 1;
          float Rm[9], Tpl[3];
#pragma unroll
          for (int k = 0; k < 9; k++) Rm[k] = sRB[(jn*12 + k)*EP + e];
#pragma unroll
          for (int k = 0; k < 3; k++) Tpl[k] = sRB[(jn*12 + 9 + k)*EP + e];
          float cFT[3];
          cross3(cFT, Fv, Tpl);
          float s0[3] = {Fw[0]+cFT[0], Fw[1]+cFT[1], Fw[2]+cFT[2]};
          float nw[3], nv[3];
          mat3T_vec(nw, Rm, s0);
          mat3T_vec(nv, Rm, Fv);
          Fw[0] = nw[0]; Fw[1] = nw[1]; Fw[2] = nw[2];
          Fv[0] = nv[0]; Fv[1] = nv[1]; Fv[2] = nv[2];
        }
        float gx = sG[i][0], gy = sG[i][1], gz = sG[i][2], m_ = sG[i][3];
        float aw[3] = {gx*Phw[i][0], gy*Phw[i][1], gz*Phw[i][2]};
        float av[3] = {m_*Phv[i][0], m_*Phv[i][1], m_*Phv[i][2]};
        float Dw[3], Dv[3];
#pragma unroll
        for (int k = 0; k < 3; k++) {
          Dw[k] = sQh[(i*6 +     k)*EP + e];
          Dv[k] = sQh[(i*6 + 3 + k)*EP + e];
        }
        float GDw[3] = {gx*Dw[0], gy*Dw[1], gz*Dw[2]};
        float GDv[3] = {m_*Dv[0], m_*Dv[1], m_*Dv[2]};
        float x1[3], x2[3], x3[3];
        cross3(x1, Phw[i], aw);   // Vw x GVw  (lane-7 semantics)
        cross3(x2, Phv[i], av);   // Vv x GVv
        cross3(x3, Phw[i], av);   // Vw x GVv
        const bool l7 = (r == 7);
#pragma unroll
        for (int k = 0; k < 3; k++) {
          Fw[k] += l7 ? (GDw[k] + x1[k] + x2[k]) : aw[k];
          Fv[k] += l7 ? (GDv[k] + x3[k])         : av[k];
        }
        float val = Fw[0]*sA[i][0] + Fw[1]*sA[i][1] + Fw[2]*sA[i][2]
                  + Fv[0]*sA[i][3] + Fv[1]*sA[i][4] + Fv[2]*sA[i][5];
        if (r < NDOF && i >= r) MllL[(i*(i+1)/2 + r)*EP + e] = val;
        if (r == 7) biasL[i*EP + e] = val;
        SCHED_FENCE();
      }
    }
    WSYNC();

    // ---- (DE) 7-lane Gauss-Jordan solve + RK4 update, lanes r<7 ----
    // Lane r owns row r of [M | rhs]. M[r][j]: j<=r from lower-tri (r,j);
    // j>r by symmetry from (j,r). SPD => diagonal pivots, no pivoting.
    // After step k, col k is zero in all non-pivot rows AND cols <k of the
    // pivot row are zero, so step k only touches cols k..7.
    if (r < NDOF) {
      float row[8];
#pragma unroll
      for (int j = 0; j < NDOF; j++) {
        int idx = (j <= r) ? (r*(r+1)/2 + j) : (j*(j+1)/2 + r);
        row[j] = MllL[idx*EP + e];
      }
      row[7] = tau - biasL[r*EP + e];
      float mydiag = 1.0f;
#pragma unroll
      for (int k = 0; k < NDOF; k++) {
        float pr[8];
#pragma unroll
        for (int j = k; j < 8; j++) pr[j] = __shfl(row[j], base + k, 64);
        if (r == k) mydiag = pr[k];
        float pinv = 1.0f / pr[k];
        float fac = (r == k) ? 0.0f : row[k] * pinv;
#pragma unroll
        for (int j = k; j < 8; j++) row[j] -= fac * pr[j];
      }
      float a = row[7] * (1.0f / mydiag);   // qacc for joint r, in register
      float w = (st == 0 || st == 3) ? 1.0f : 2.0f;
      accq += w * dqs;
      accd += w * a;
      if (st < 3) {
        float c = (st == 2) ? HSTEP : 0.5f*HSTEP;
        qs  = q0  + c * dqs;
        dqs = dq0 + c * a;
      }
    }
    WSYNC();
  }

  const float h6 = HSTEP / 6.0f;
  float qf = 0.f;
  if (r < NDOF) {
    qf = wrap_pi(q0 + h6*accq);
    float v  = dq0 + h6*accd;
    float dqf = fminf(fmaxf(v, -MAX_VEL), MAX_VEL);
    g_out_state[b*14 + r]     = qf;
    g_out_state[b*14 + 7 + r] = dqf;
  }

  // ---- FK: per-lane leaf + 3-step shuffle tree over the 8-lane group ----
  // lane r<7: T_r = M_r * exp(A_r, qf_r); lane 7: T_7 = M_7.
  // Leftward product: lane 0 ends with (M_0 E_0)...(M_6 E_6) M_7; its p is EE.
  float SR[9], Sp[3];
  {
    float MR[9];
#pragma unroll
    for (int k = 0; k < 9; k++) MR[k] = sMR[r][k];
    float Mpl[3] = {sMp[r][0], sMp[r][1], sMp[r][2]};
    if (r < NDOF) {
      float Ai[6];
#pragma unroll
      for (int k = 0; k < 6; k++) Ai[k] = sA[r][k];
      float Re[9], pe[3];
      exp_se3(Ai, qf, Re, pe);
      mat3_mul(SR, MR, Re);
      float t[3];
      mat3_vec(t, MR, pe);
      Sp[0] = t[0] + Mpl[0]; Sp[1] = t[1] + Mpl[1]; Sp[2] = t[2] + Mpl[2];
    } else {
#pragma unroll
      for (int k = 0; k < 9; k++) SR[k] = MR[k];
      Sp[0] = Mpl[0]; Sp[1] = Mpl[1]; Sp[2] = Mpl[2];
    }
  }
#pragma unroll
  for (int off = 1; off < 8; off <<= 1) {
    const int partner = base + ((r + off) & 7);
    float PRm[9], Pp[3];
#pragma unroll
    for (int k = 0; k < 9; k++) PRm[k] = __shfl(SR[k], partner, 64);
#pragma unroll
    for (int k = 0; k < 3; k++) Pp[k] = __shfl(Sp[k], partner, 64);
    float NR[9], Np[3];
    mat3_mul(NR, SR, PRm);
    mat3_vec(Np, SR, Pp);
    Np[0] += Sp[0]; Np[1] += Sp[1]; Np[2] += Sp[2];
#pragma unroll
    for (int k = 0; k < 9; k++) SR[k] = NR[k];
    Sp[0] = Np[0]; Sp[1] = Np[1]; Sp[2] = Np[2];
  }
  if (r == 0) {
    g_out_ee[b*2 + 0] = Sp[0];
    g_out_ee[b*2 + 1] = Sp[1];
  }
}

extern "C" void kernel_launch(void* const* d_in, const int* in_sizes, int n_in,
                              void* d_out, int out_size, void* d_ws, size_t ws_size,
                              hipStream_t stream) {
  const float* state  = (const float*)d_in[0];  // (16384,14)
  const float* action = (const float*)d_in[1];  // (16384,7)
  const float* M      = (const float*)d_in[2];  // (8,4,4)
  const float* A      = (const float*)d_in[3];  // (7,6)
  const float* G      = (const float*)d_in[4];  // (7,4)
  const float* grav   = (const float*)d_in[5];  // (3,)
  float* out_state = (float*)d_out;                       // (16384,14)
  float* out_ee    = (float*)d_out + (size_t)BATCH * 14;  // (16384,2)

  arm_rk4_kernel<<<BATCH / EPB, BLOCK, 0, stream>>>(
      state, action, M, A, G, grav, out_state, out_ee);
}